// Round 1
// baseline (117.437 us; speedup 1.0000x reference)
//
#include <hip/hip_runtime.h>

#define BATCH 1048576
#define HIDDEN 64

// One thread computes TWO adjacent rows (2t, 2t+1):
//  - loads 20 consecutive floats (80B) as 5x float4 -> fully coalesced
//  - paired row0/row1 FMA chains invite v_pk_fma_f32 formation
__global__ __launch_bounds__(256) void simplenn_kernel(
    const float* __restrict__ x,     // (B,10)
    const float* __restrict__ gate,  // (4,)
    const float* __restrict__ w1,    // (2,64) row-major: w1[0][h]=w1[h], w1[1][h]=w1[64+h]
    const float* __restrict__ b1,    // (64,)
    const float* __restrict__ w2,    // (64,)
    const float* __restrict__ b2,    // (1,)
    float* __restrict__ out)         // (B,5)
{
    const int t = blockIdx.x * blockDim.x + threadIdx.x;   // row pair index

    // ---- argmax(gate_logits), first-max semantics (wave-uniform) ----
    float g0 = gate[0], g1 = gate[1], g2 = gate[2], g3 = gate[3];
    int idx = 0; float gm = g0;
    if (g1 > gm) { gm = g1; idx = 1; }
    if (g2 > gm) { gm = g2; idx = 2; }
    if (g3 > gm) { gm = g3; idx = 3; }

    // ---- load 2 rows = 20 floats, coalesced float4 ----
    const float4* xv = (const float4*)(x + (size_t)t * 20);
    float4 q0 = xv[0], q1 = xv[1], q2 = xv[2], q3 = xv[3], q4 = xv[4];
    float v[20] = { q0.x,q0.y,q0.z,q0.w, q1.x,q1.y,q1.z,q1.w,
                    q2.x,q2.y,q2.z,q2.w, q3.x,q3.y,q3.z,q3.w,
                    q4.x,q4.y,q4.z,q4.w };

    // ---- selected transform (uniform branch) ----
    if (idx == 1) {
        #pragma unroll
        for (int j = 0; j < 20; ++j) v[j] = __logf(v[j]);
    } else if (idx == 2) {
        #pragma unroll
        for (int j = 0; j < 20; ++j) v[j] = __expf(v[j]);
    } else if (idx == 3) {
        #pragma unroll
        for (int j = 0; j < 20; ++j) v[j] = __sinf(v[j]);
    }
    // v[0..4]=wi row0, v[5..9]=pi row0, v[10..14]=wi row1, v[15..19]=pi row1

    // ---- tiny MLP: h = relu(wi*w1_0 + pi*w1_1 + b1); out = h . w2 + b2 ----
    float acc[10];
    const float bias2 = b2[0];
    #pragma unroll
    for (int i = 0; i < 10; ++i) acc[i] = bias2;

    #pragma unroll 8
    for (int h = 0; h < HIDDEN; ++h) {
        const float a  = w1[h];          // w1[0][h]
        const float c  = w1[HIDDEN + h]; // w1[1][h]
        const float bb = b1[h];
        const float w  = w2[h];
        #pragma unroll
        for (int i = 0; i < 5; ++i) {
            float t0 = fmaf(v[i],      a, fmaf(v[i + 5],  c, bb));
            float t1 = fmaf(v[10 + i], a, fmaf(v[15 + i], c, bb));
            t0 = fmaxf(t0, 0.f);
            t1 = fmaxf(t1, 0.f);
            acc[i]     = fmaf(t0, w, acc[i]);
            acc[5 + i] = fmaf(t1, w, acc[5 + i]);
        }
    }

    // ---- store 10 consecutive floats (40B) as 5x float2 (8B aligned always) ----
    float2* o = (float2*)(out + (size_t)t * 10);
    o[0] = make_float2(acc[0], acc[1]);
    o[1] = make_float2(acc[2], acc[3]);
    o[2] = make_float2(acc[4], acc[5]);
    o[3] = make_float2(acc[6], acc[7]);
    o[4] = make_float2(acc[8], acc[9]);
}

extern "C" void kernel_launch(void* const* d_in, const int* in_sizes, int n_in,
                              void* d_out, int out_size, void* d_ws, size_t ws_size,
                              hipStream_t stream) {
    const float* x    = (const float*)d_in[0];
    const float* gate = (const float*)d_in[1];
    const float* w1   = (const float*)d_in[2];
    const float* b1   = (const float*)d_in[3];
    const float* w2   = (const float*)d_in[4];
    const float* b2   = (const float*)d_in[5];
    float* out = (float*)d_out;

    const int n_threads = BATCH / 2;          // 524288 row-pairs
    const int block = 256;
    const int grid = n_threads / block;       // 2048 blocks, exact
    simplenn_kernel<<<grid, block, 0, stream>>>(x, gate, w1, b1, w2, b2, out);
}

// Round 3
// 108.322 us; speedup vs baseline: 1.0842x; 1.0842x over previous
//
#include <hip/hip_runtime.h>

#define BATCH 1048576
#define HIDDEN 64

// fp16x2 packed math: .x = row 2t, .y = row 2t+1
typedef _Float16 h2 __attribute__((ext_vector_type(2)));

static __device__ __forceinline__ h2 pack2(float a, float b) {
    // cvt_pkrtz returns __fp16x2; bit-identical to _Float16x2
    return __builtin_bit_cast(h2, __builtin_amdgcn_cvt_pkrtz(a, b));
}

__global__ __launch_bounds__(256) void simplenn_kernel(
    const float* __restrict__ x,     // (B,10)
    const float* __restrict__ gate,  // (4,)
    const float* __restrict__ w1,    // (2,64)
    const float* __restrict__ b1,    // (64,)
    const float* __restrict__ w2,    // (64,)
    const float* __restrict__ b2,    // (1,)
    float* __restrict__ out)         // (B,5)
{
    // Pre-packed broadcast weight pairs in LDS: one uniform ds_read_b128/h
    // in the hot loop (LDS pipe, not VALU). 1 KiB.
    __shared__ __align__(16) h2 lw[HIDDEN][4];   // {a,a},{c,c},{b,b},{w,w}

    const int tid = threadIdx.x;
    if (tid < HIDDEN) {
        float a = w1[tid], c = w1[HIDDEN + tid], bb = b1[tid], w = w2[tid];
        lw[tid][0] = pack2(a, a);
        lw[tid][1] = pack2(c, c);
        lw[tid][2] = pack2(bb, bb);
        lw[tid][3] = pack2(w, w);
    }

    // argmax(gate_logits), first-max semantics (wave-uniform branch)
    float g0 = gate[0], g1 = gate[1], g2 = gate[2], g3 = gate[3];
    int idx = 0; float gm = g0;
    if (g1 > gm) { gm = g1; idx = 1; }
    if (g2 > gm) { gm = g2; idx = 2; }
    if (g3 > gm) { gm = g3; idx = 3; }

    // 2 rows/thread: 80B contiguous, 5x float4, fully coalesced
    const int t = blockIdx.x * blockDim.x + tid;
    const float4* xv = (const float4*)(x + (size_t)t * 20);
    float4 q0 = xv[0], q1 = xv[1], q2 = xv[2], q3 = xv[3], q4 = xv[4];
    float v[20] = { q0.x,q0.y,q0.z,q0.w, q1.x,q1.y,q1.z,q1.w,
                    q2.x,q2.y,q2.z,q2.w, q3.x,q3.y,q3.z,q3.w,
                    q4.x,q4.y,q4.z,q4.w };

    if (idx == 1) {
        #pragma unroll
        for (int j = 0; j < 20; ++j) v[j] = __logf(v[j]);
    } else if (idx == 2) {
        #pragma unroll
        for (int j = 0; j < 20; ++j) v[j] = __expf(v[j]);
    } else if (idx == 3) {
        #pragma unroll
        for (int j = 0; j < 20; ++j) v[j] = __sinf(v[j]);
    }
    // v[0..4]=wi r0, v[5..9]=pi r0, v[10..14]=wi r1, v[15..19]=pi r1

    __syncthreads();   // lw ready

    // pack inputs: pair i = (row0[i], row1[i])
    h2 wiP[5], piP[5];
    #pragma unroll
    for (int i = 0; i < 5; ++i) {
        wiP[i] = pack2(v[i],     v[10 + i]);
        piP[i] = pack2(v[5 + i], v[15 + i]);
    }

    const h2 zero = { (_Float16)0, (_Float16)0 };
    const float bias2 = b2[0];
    float accx[5], accy[5];
    #pragma unroll
    for (int i = 0; i < 5; ++i) { accx[i] = bias2; accy[i] = bias2; }

    // 4 segments of 16 h: fp16x2 accumulate within, fp32 flush between
    for (int seg = 0; seg < 4; ++seg) {
        h2 acc[5];
        #pragma unroll
        for (int i = 0; i < 5; ++i) acc[i] = zero;

        #pragma unroll
        for (int k = 0; k < 16; ++k) {
            const int h = seg * 16 + k;
            h2 aa = lw[h][0], cc = lw[h][1], bp = lw[h][2], wp = lw[h][3];
            #pragma unroll
            for (int i = 0; i < 5; ++i) {
                h2 pre = __builtin_elementwise_fma(piP[i], cc, bp);
                pre    = __builtin_elementwise_fma(wiP[i], aa, pre);
                pre    = __builtin_elementwise_max(pre, zero);
                acc[i] = __builtin_elementwise_fma(pre, wp, acc[i]);
            }
        }
        #pragma unroll
        for (int i = 0; i < 5; ++i) {
            accx[i] += (float)acc[i].x;
            accy[i] += (float)acc[i].y;
        }
    }

    // store 10 consecutive floats (40B) as 5x float2
    float2* o = (float2*)(out + (size_t)t * 10);
    o[0] = make_float2(accx[0], accx[1]);
    o[1] = make_float2(accx[2], accx[3]);
    o[2] = make_float2(accx[4], accy[0]);
    o[3] = make_float2(accy[1], accy[2]);
    o[4] = make_float2(accy[3], accy[4]);
}

extern "C" void kernel_launch(void* const* d_in, const int* in_sizes, int n_in,
                              void* d_out, int out_size, void* d_ws, size_t ws_size,
                              hipStream_t stream) {
    const float* x    = (const float*)d_in[0];
    const float* gate = (const float*)d_in[1];
    const float* w1   = (const float*)d_in[2];
    const float* b1   = (const float*)d_in[3];
    const float* w2   = (const float*)d_in[4];
    const float* b2   = (const float*)d_in[5];
    float* out = (float*)d_out;

    const int n_threads = BATCH / 2;          // 524288 row-pairs
    const int block = 256;
    const int grid = n_threads / block;       // 2048 blocks
    simplenn_kernel<<<grid, block, 0, stream>>>(x, gate, w1, b1, w2, b2, out);
}

// Round 4
// 105.500 us; speedup vs baseline: 1.1132x; 1.0267x over previous
//
#include <hip/hip_runtime.h>

#define BATCH 1048576
#define HIDDEN 64

// fp16x2: packed across adjacent hidden units (h, h+1)
typedef _Float16 h2 __attribute__((ext_vector_type(2)));

static __device__ __forceinline__ h2 pack2(float a, float b) {
    // cvt_pkrtz returns __fp16x2; bit-identical to _Float16x2
    return __builtin_bit_cast(h2, __builtin_amdgcn_cvt_pkrtz(a, b));
}

__global__ __launch_bounds__(256) void simplenn_kernel(
    const float* __restrict__ x,     // (B,10)
    const float* __restrict__ gate,  // (4,)
    const float* __restrict__ w1,    // (2,64)
    const float* __restrict__ b1,    // (64,)
    const float* __restrict__ w2,    // (64,)
    const float* __restrict__ b2,    // (1,)
    float* __restrict__ out)         // (B,5)
{
    // LDS weights packed by h-pair: {a,a'},{c,c'},{b,b'},{w,w'} = 16B/pair.
    // One uniform ds_read_b128 per h-pair in the hot loop (32 total). 512B.
    __shared__ __align__(16) h2 lw[HIDDEN / 2][4];

    const int tid = threadIdx.x;
    if (tid < HIDDEN / 2) {
        const int h0 = 2 * tid, h1 = 2 * tid + 1;
        lw[tid][0] = pack2(w1[h0],          w1[h1]);           // a pair
        lw[tid][1] = pack2(w1[HIDDEN + h0], w1[HIDDEN + h1]);  // c pair
        lw[tid][2] = pack2(b1[h0],          b1[h1]);           // b pair
        lw[tid][3] = pack2(w2[h0],          w2[h1]);           // w pair
    }

    // argmax(gate_logits), first-max semantics (wave-uniform branch)
    float g0 = gate[0], g1 = gate[1], g2 = gate[2], g3 = gate[3];
    int idx = 0; float gm = g0;
    if (g1 > gm) { gm = g1; idx = 1; }
    if (g2 > gm) { gm = g2; idx = 2; }
    if (g3 > gm) { gm = g3; idx = 3; }

    // 2 rows/thread: 80B contiguous, 5x float4, fully coalesced
    const int t = blockIdx.x * blockDim.x + tid;
    const float4* xv = (const float4*)(x + (size_t)t * 20);
    float4 q0 = xv[0], q1 = xv[1], q2 = xv[2], q3 = xv[3], q4 = xv[4];
    float v[20] = { q0.x,q0.y,q0.z,q0.w, q1.x,q1.y,q1.z,q1.w,
                    q2.x,q2.y,q2.z,q2.w, q3.x,q3.y,q3.z,q3.w,
                    q4.x,q4.y,q4.z,q4.w };

    if (idx == 1) {
        #pragma unroll
        for (int j = 0; j < 20; ++j) v[j] = __logf(v[j]);
    } else if (idx == 2) {
        #pragma unroll
        for (int j = 0; j < 20; ++j) v[j] = __expf(v[j]);
    } else if (idx == 3) {
        #pragma unroll
        for (int j = 0; j < 20; ++j) v[j] = __sinf(v[j]);
    }
    // v[0..4]=wi r0, v[5..9]=pi r0, v[10..14]=wi r1, v[15..19]=pi r1

    __syncthreads();   // lw ready

    // broadcast-pack inputs: (v,v) so both halves of the h-pair see the same x
    h2 wiB[10], piB[10];   // j = r*5 + i
    #pragma unroll
    for (int i = 0; i < 5; ++i) {
        wiB[i]     = pack2(v[i],      v[i]);
        piB[i]     = pack2(v[5 + i],  v[5 + i]);
        wiB[5 + i] = pack2(v[10 + i], v[10 + i]);
        piB[5 + i] = pack2(v[15 + i], v[15 + i]);
    }

    const h2 zero = { (_Float16)0, (_Float16)0 };
    const float bias2 = b2[0];
    float acc[10];   // fp32 accumulators: no flush needed, fdot2 accumulates f32
    #pragma unroll
    for (int j = 0; j < 10; ++j) acc[j] = bias2;

    #pragma unroll 8
    for (int hp = 0; hp < HIDDEN / 2; ++hp) {
        const h2 aa = lw[hp][0], cc = lw[hp][1], bb = lw[hp][2], ww = lw[hp][3];
        #pragma unroll
        for (int j = 0; j < 10; ++j) {
            h2 pre = __builtin_elementwise_fma(piB[j], cc, bb);   // v_pk_fma_f16
            pre    = __builtin_elementwise_fma(wiB[j], aa, pre);  // v_pk_fma_f16
            pre    = __builtin_elementwise_max(pre, zero);        // v_pk_max_f16
            acc[j] = __builtin_amdgcn_fdot2(pre, ww, acc[j], false); // v_dot2_f32_f16
        }
    }

    // store 10 consecutive floats (40B) as 5x float2
    float2* o = (float2*)(out + (size_t)t * 10);
    o[0] = make_float2(acc[0], acc[1]);
    o[1] = make_float2(acc[2], acc[3]);
    o[2] = make_float2(acc[4], acc[5]);
    o[3] = make_float2(acc[6], acc[7]);
    o[4] = make_float2(acc[8], acc[9]);
}

extern "C" void kernel_launch(void* const* d_in, const int* in_sizes, int n_in,
                              void* d_out, int out_size, void* d_ws, size_t ws_size,
                              hipStream_t stream) {
    const float* x    = (const float*)d_in[0];
    const float* gate = (const float*)d_in[1];
    const float* w1   = (const float*)d_in[2];
    const float* b1   = (const float*)d_in[3];
    const float* w2   = (const float*)d_in[4];
    const float* b2   = (const float*)d_in[5];
    float* out = (float*)d_out;

    const int n_threads = BATCH / 2;          // 524288 row-pairs
    const int block = 256;
    const int grid = n_threads / block;       // 2048 blocks
    simplenn_kernel<<<grid, block, 0, stream>>>(x, gate, w1, b1, w2, b2, out);
}